// Round 11
// baseline (285.917 us; speedup 1.0000x reference)
//
#include <hip/hip_runtime.h>
#include <float.h>

#define N_PTS 6144
#define D_IN  512
#define H1_DIM 256
#define H2_DIM 128
#define G_DIM  64
#define KNN    32
#define NOUT   22
#define ROWS   4

typedef short s8v __attribute__((ext_vector_type(8)));   // 8 bf16 in 4 VGPR
typedef float f32x4 __attribute__((ext_vector_type(4)));
typedef unsigned u32x4 __attribute__((ext_vector_type(4)));
typedef unsigned short u16;
typedef unsigned long long u64;

__device__ __forceinline__ u16 f2bf(float f) {
  unsigned u = __float_as_uint(f);
  u += 0x7FFFu + ((u >> 16) & 1u);          // RNE to bf16
  return (u16)(u >> 16);
}
__device__ __forceinline__ float bf2f(u16 s) {
  return __uint_as_float(((unsigned)s) << 16);
}
__device__ __forceinline__ void split3(float v, u16& a0, u16& a1, u16& a2) {
  a0 = f2bf(v);
  float r1 = v - bf2f(a0);
  a1 = f2bf(r1);
  a2 = f2bf(r1 - bf2f(a1));
}

// ---------------------------------------------------------------------------
// MFMA GEMM, 3-way bf16 split, 6-term schedule (fp32-equivalent).
// C[M,N] = A[M,K] * B^T[N,K].  BN=64, BK=32, 4 waves (2x2), wave tile (BM/2)x32.
// WKEY: epilogue writes sortable-u32 kNN keys (sq[col] - 2*val; diag=UINT_MAX).
// ---------------------------------------------------------------------------
template<int BM, bool AF32, bool SPLITK, bool BIAS, bool RELU, bool WF32, bool WSPLIT, bool WKEY>
__global__ __launch_bounds__(256, 4) void mfma_gemm(
    const void* __restrict__ A0any, const u16* __restrict__ A1_, const u16* __restrict__ A2_,
    const u16* __restrict__ B0_, const u16* __restrict__ B1_, const u16* __restrict__ B2_,
    const float* __restrict__ bias,
    float* __restrict__ Cf, u16* __restrict__ C0, u16* __restrict__ C1, u16* __restrict__ C2,
    int Ktot, int Ks, int ldC, size_t MN, int rowoff)
{
  const int MT = BM / 32, NT = 2;
  __shared__ u16 lds[(BM + 64) * 32 * 3];
  u16* Ap[3] = { lds, lds + BM * 32, lds + 2 * BM * 32 };
  u16* Bp[3] = { lds + 3 * BM * 32, lds + 3 * BM * 32 + 2048, lds + 3 * BM * 32 + 4096 };

  const int t = threadIdx.x;
  const int lane = t & 63, wave = t >> 6;
  const int wm = wave >> 1, wn = wave & 1;
  const int m0 = blockIdx.y * BM, n0 = blockIdx.x * 64;
  const int kz = blockIdx.z * Ks;

  f32x4 acc[MT][NT] = {};

  for (int k0 = 0; k0 < Ks; k0 += 32) {
    if (k0) __syncthreads();
    const int kb = kz + k0;
    if (AF32) {
      const float* A = (const float*)A0any;
      #pragma unroll
      for (int c0 = 0; c0 < BM * 4; c0 += 256) {
        int c = c0 + t;
        int row = c >> 2, slot = c & 3;
        const float* g = A + (size_t)(m0 + row) * Ktot + kb + slot * 8;
        f32x4 fa = *(const f32x4*)g;
        f32x4 fb = *(const f32x4*)(g + 4);
        int dst = row * 32 + ((slot ^ ((row >> 1) & 3)) << 3);
        s8v v0, v1, v2;
        #pragma unroll
        for (int e = 0; e < 4; ++e) {
          u16 a0, a1, a2; split3(fa[e], a0, a1, a2);
          v0[e] = (short)a0; v1[e] = (short)a1; v2[e] = (short)a2;
        }
        #pragma unroll
        for (int e = 0; e < 4; ++e) {
          u16 a0, a1, a2; split3(fb[e], a0, a1, a2);
          v0[4 + e] = (short)a0; v1[4 + e] = (short)a1; v2[4 + e] = (short)a2;
        }
        *(s8v*)(Ap[0] + dst) = v0;
        *(s8v*)(Ap[1] + dst) = v1;
        *(s8v*)(Ap[2] + dst) = v2;
      }
    } else {
      const u16* As[3] = { (const u16*)A0any, A1_, A2_ };
      #pragma unroll
      for (int c0 = 0; c0 < BM * 4; c0 += 256) {
        int c = c0 + t;
        int row = c >> 2, slot = c & 3;
        size_t g = (size_t)(m0 + row) * Ktot + kb + slot * 8;
        int dst = row * 32 + ((slot ^ ((row >> 1) & 3)) << 3);
        #pragma unroll
        for (int p = 0; p < 3; ++p)
          *(s8v*)(Ap[p] + dst) = *(const s8v*)(As[p] + g);
      }
    }
    {
      const u16* Bs[3] = { B0_, B1_, B2_ };
      int row = t >> 2, slot = t & 3;
      size_t g = (size_t)(n0 + row) * Ktot + kb + slot * 8;
      int dst = row * 32 + ((slot ^ ((row >> 1) & 3)) << 3);
      #pragma unroll
      for (int p = 0; p < 3; ++p)
        *(s8v*)(Bp[p] + dst) = *(const s8v*)(Bs[p] + g);
    }
    __syncthreads();

    s8v af[3][MT], bf[3][NT];
    #pragma unroll
    for (int mt = 0; mt < MT; ++mt) {
      int r = wm * (BM / 2) + mt * 16 + (lane & 15);
      int off = r * 32 + (((lane >> 4) ^ ((r >> 1) & 3)) << 3);
      #pragma unroll
      for (int p = 0; p < 3; ++p) af[p][mt] = *(const s8v*)(Ap[p] + off);
    }
    #pragma unroll
    for (int nt = 0; nt < NT; ++nt) {
      int r = wn * 32 + nt * 16 + (lane & 15);
      int off = r * 32 + (((lane >> 4) ^ ((r >> 1) & 3)) << 3);
      #pragma unroll
      for (int p = 0; p < 3; ++p) bf[p][nt] = *(const s8v*)(Bp[p] + off);
    }
    #pragma unroll
    for (int mt = 0; mt < MT; ++mt)
      #pragma unroll
      for (int nt = 0; nt < NT; ++nt) {
        f32x4 a = acc[mt][nt];
        a = __builtin_amdgcn_mfma_f32_16x16x32_bf16(af[0][mt], bf[0][nt], a, 0, 0, 0);
        a = __builtin_amdgcn_mfma_f32_16x16x32_bf16(af[0][mt], bf[1][nt], a, 0, 0, 0);
        a = __builtin_amdgcn_mfma_f32_16x16x32_bf16(af[1][mt], bf[0][nt], a, 0, 0, 0);
        a = __builtin_amdgcn_mfma_f32_16x16x32_bf16(af[1][mt], bf[1][nt], a, 0, 0, 0);
        a = __builtin_amdgcn_mfma_f32_16x16x32_bf16(af[0][mt], bf[2][nt], a, 0, 0, 0);
        a = __builtin_amdgcn_mfma_f32_16x16x32_bf16(af[2][mt], bf[0][nt], a, 0, 0, 0);
        acc[mt][nt] = a;
      }
  }

  #pragma unroll
  for (int mt = 0; mt < MT; ++mt) {
    #pragma unroll
    for (int nt = 0; nt < NT; ++nt) {
      int col = n0 + wn * 32 + nt * 16 + (lane & 15);
      float bv = (BIAS && !SPLITK) ? bias[col] : 0.f;
      float sqc = WKEY ? bias[col] : 0.f;
      #pragma unroll
      for (int v = 0; v < 4; ++v) {
        int row = m0 + wm * (BM / 2) + mt * 16 + (lane >> 4) * 4 + v;
        float val = acc[mt][nt][v] + bv;
        size_t o = (size_t)row * ldC + col;
        if (SPLITK) {
          Cf[(size_t)blockIdx.z * MN + o] = val;
        } else if (WKEY) {
          float f = fmaf(-2.f, val, sqc);
          unsigned ub = __float_as_uint(f);
          unsigned uu = (ub & 0x80000000u) ? ~ub : (ub | 0x80000000u);
          if (rowoff + row == col) uu = 0xFFFFFFFFu;
          ((unsigned*)Cf)[o] = uu;
        } else {
          if (RELU) val = fmaxf(val, 0.f);
          if (WF32) Cf[o] = val;
          if (WSPLIT) {
            u16 a0, a1, a2; split3(val, a0, a1, a2);
            C0[o] = a0; C1[o] = a1; C2[o] = a2;
          }
        }
      }
    }
  }
}

template<int S, bool BIAS, bool RELU, bool WF32, bool WSPLIT>
__global__ void combine(const float* __restrict__ P, const float* __restrict__ bias,
                        size_t MN, int Ncols,
                        float* __restrict__ Cf, u16* __restrict__ C0,
                        u16* __restrict__ C1, u16* __restrict__ C2)
{
  size_t idx = ((size_t)blockIdx.x * 256 + threadIdx.x) * 4;
  if (idx >= MN) return;
  f32x4 s = *(const f32x4*)(P + idx);
  #pragma unroll
  for (int z = 1; z < S; ++z) s += *(const f32x4*)(P + (size_t)z * MN + idx);
  int n = (int)(idx % (size_t)Ncols);
  #pragma unroll
  for (int e = 0; e < 4; ++e) {
    float v = s[e] + (BIAS ? bias[n + e] : 0.f);
    if (RELU) v = fmaxf(v, 0.f);
    if (WF32) Cf[idx + e] = v;
    if (WSPLIT) {
      u16 a0, a1, a2; split3(v, a0, a1, a2);
      C0[idx + e] = a0; C1[idx + e] = a1; C2[idx + e] = a2;
    }
  }
}

__global__ void trans_split(const float* __restrict__ W, u16* __restrict__ p0,
                            u16* __restrict__ p1, u16* __restrict__ p2, int K, int N)
{
  int id = blockIdx.x * 256 + threadIdx.x;
  if (id >= K * N) return;
  int k = id / N, n = id % N;
  u16 a0, a1, a2;
  split3(W[id], a0, a1, a2);
  size_t o = (size_t)n * K + k;
  p0[o] = a0; p1[o] = a1; p2[o] = a2;
}

__global__ void prep_head(const float* __restrict__ cW, const float* __restrict__ cb,
                          const float* __restrict__ dW, const float* __restrict__ db,
                          float* __restrict__ Wc, float* __restrict__ bc)
{
  int t = threadIdx.x;
  for (int idx = t; idx < 64 * NOUT; idx += 256) {
    int g = idx / NOUT, c = idx % NOUT;
    float s = 0.f;
    if (c < 16) {
      for (int r = 0; r < 8; ++r) s += cW[(r * 64 + g) * 16 + c];
    } else {
      int k = (c - 16) >> 1, o = (c - 16) & 1;
      for (int r = 0; r < 8; ++r) s += dW[k * 1024 + (r * 64 + g) * 2 + o];
    }
    Wc[idx] = s;
  }
  if (t < NOUT) bc[t] = (t < 16) ? cb[t] : db[t - 16];
}

__global__ void row_stats(const float* __restrict__ h, const float* __restrict__ Wh,
                          const float* __restrict__ ga, float* __restrict__ sq,
                          float* __restrict__ f1, float* __restrict__ f2)
{
  int i = blockIdx.x * 256 + threadIdx.x;
  const float* hr = h + (size_t)i * H2_DIM;
  float s = 0.f;
  for (int k = 0; k < H2_DIM; ++k) { float v = hr[k]; s = fmaf(v, v, s); }
  sq[i] = s;
  const float* wr = Wh + (size_t)i * G_DIM;
  float a = 0.f, b = 0.f;
  for (int g = 0; g < G_DIM; ++g) {
    float w = wr[g];
    a = fmaf(w, ga[g], a);
    b = fmaf(w, ga[G_DIM + g], b);
  }
  f1[i] = a; f2[i] = b;
}

// ---------------------------------------------------------------------------
// ROWS rows per block. Per row: quad-min tournament -> quaternary bisection
// (r9-proven) for Q = exact 32nd-smallest quad-min -> collect qualifying
// quads -> 256-wide bitonic on (key<<13|j) -> exact top-32 with np tie-break.
// Next row's 24.6KB key load is prefetched into registers during the current
// row's selection (hides HBM/L3 latency); WcL loaded once per block.
// Then fused masked softmax + sparse att@Wh + elu + 64->22 head per row.
// ---------------------------------------------------------------------------
__global__ __launch_bounds__(256) void topk_att(const unsigned* __restrict__ Sb,
    const float* __restrict__ f1, const float* __restrict__ f2,
    const float* __restrict__ Wh, const float* __restrict__ Wc, const float* __restrict__ bc,
    float* __restrict__ out, int m0)
{
  const int t = threadIdx.x;
  const int lane = t & 63, wv = t >> 6;
  const int rbase = m0 + blockIdx.x * ROWS;

  __shared__ int wsum[3][4];
  __shared__ unsigned wmn[4], wmx[4];
  __shared__ int qcnt;
  __shared__ u64 cand[256];
  __shared__ u64 redr[4];
  __shared__ int neigh[33];
  __shared__ float attL[33];
  __shared__ float hp4[4][64];
  __shared__ float hpf[64];
  __shared__ float WcL[64 * NOUT];

  for (int idx = t; idx < 64 * NOUT; idx += 256) WcL[idx] = Wc[idx];

  unsigned u[24], uN[24];
  {
    const unsigned* Srow = Sb + (size_t)(blockIdx.x * ROWS) * N_PTS;
    #pragma unroll
    for (int c = 0; c < 6; ++c) {
      u32x4 v = *(const u32x4*)(Srow + (c << 10) + (t << 2));
      #pragma unroll
      for (int e = 0; e < 4; ++e) u[c * 4 + e] = v[e];
    }
  }
  #define JOF(m) ((((m) >> 2) << 10) + (t << 2) + ((m) & 3))

  for (int r = 0; r < ROWS; ++r) {
    const int i = rbase + r;

    // issue next row's key loads early (hidden under this row's compute)
    if (r < ROWS - 1) {
      const unsigned* SrowN = Sb + (size_t)(blockIdx.x * ROWS + r + 1) * N_PTS;
      #pragma unroll
      for (int c = 0; c < 6; ++c) {
        u32x4 v = *(const u32x4*)(SrowN + (c << 10) + (t << 2));
        #pragma unroll
        for (int e = 0; e < 4; ++e) uN[c * 4 + e] = v[e];
      }
    }

    if (t == 0) qcnt = 0;
    cand[t] = ~0ull;

    // quad-min tournament
    unsigned q[6];
    #pragma unroll
    for (int c = 0; c < 6; ++c) {
      unsigned a = u[c * 4] < u[c * 4 + 1] ? u[c * 4] : u[c * 4 + 1];
      unsigned b = u[c * 4 + 2] < u[c * 4 + 3] ? u[c * 4 + 2] : u[c * 4 + 3];
      q[c] = a < b ? a : b;
    }
    unsigned tm = q[0];
    #pragma unroll
    for (int c = 1; c < 6; ++c) tm = q[c] < tm ? q[c] : tm;

    // interval: lo = blockmin-1; hi = min over waves of max-of-lane-mins
    unsigned mnl = tm, mxl = tm;
    #pragma unroll
    for (int off = 32; off > 0; off >>= 1) {
      unsigned o1 = __shfl_xor(mnl, off); mnl = o1 < mnl ? o1 : mnl;
      unsigned o2 = __shfl_xor(mxl, off); mxl = o2 > mxl ? o2 : mxl;
    }
    if (lane == 0) { wmn[wv] = mnl; wmx[wv] = mxl; }
    __syncthreads();
    unsigned mn = wmn[0], ub = wmx[0];
    #pragma unroll
    for (int w2 = 1; w2 < 4; ++w2) {
      mn = wmn[w2] < mn ? wmn[w2] : mn;
      ub = wmx[w2] < ub ? wmx[w2] : ub;
    }

    // quaternary bisection on quad-mins: Q = exact 32nd-smallest quad-min
    long long lo = (long long)mn - 1, hi = (long long)ub;
    while (hi - lo > 1) {
      long long span = hi - lo;
      unsigned m1 = (unsigned)(lo + (span >> 2));
      unsigned m2 = (unsigned)(lo + (span >> 1));
      unsigned m3 = (unsigned)(hi - (span >> 2));
      int c1 = 0, c2 = 0, c3 = 0;
      #pragma unroll
      for (int c = 0; c < 6; ++c) {
        c1 += (q[c] <= m1);
        c2 += (q[c] <= m2);
        c3 += (q[c] <= m3);
      }
      #pragma unroll
      for (int off = 32; off > 0; off >>= 1) {
        c1 += __shfl_xor(c1, off);
        c2 += __shfl_xor(c2, off);
        c3 += __shfl_xor(c3, off);
      }
      if (lane == 0) { wsum[0][wv] = c1; wsum[1][wv] = c2; wsum[2][wv] = c3; }
      __syncthreads();
      int t1 = wsum[0][0] + wsum[0][1] + wsum[0][2] + wsum[0][3];
      int t2 = wsum[1][0] + wsum[1][1] + wsum[1][2] + wsum[1][3];
      int t3 = wsum[2][0] + wsum[2][1] + wsum[2][2] + wsum[2][3];
      __syncthreads();
      if (t1 >= KNN)       { hi = m1; }
      else if (t2 >= KNN)  { lo = m1; hi = m2; }
      else if (t3 >= KNN)  { lo = m2; hi = m3; }
      else                 { lo = m3; }
    }
    const unsigned Q = (unsigned)hi;

    // collect qualifying quads (min <= Q) -> candidate u64 ranks
    #pragma unroll
    for (int c = 0; c < 6; ++c) {
      if (q[c] <= Q) {
        int pos = atomicAdd(&qcnt, 1);
        if (pos < 64) {
          #pragma unroll
          for (int e = 0; e < 4; ++e) {
            int j = (c << 10) + (t << 2) + e;
            cand[pos * 4 + e] = ((u64)u[c * 4 + e] << 13) | (unsigned)j;
          }
        }
      }
    }
    __syncthreads();

    if (qcnt <= 64) {
      // block bitonic sort of 256 candidates, 1 element/thread
      u64 v = cand[t];
      __syncthreads();
      for (int k = 2; k <= 256; k <<= 1) {
        for (int j2 = k >> 1; j2 >= 1; j2 >>= 1) {
          u64 o;
          if (j2 >= 64) {
            cand[t] = v;
            __syncthreads();
            o = cand[t ^ j2];
            __syncthreads();
          } else {
            o = __shfl_xor(v, j2);
          }
          bool keepMin = ((t & k) == 0) == ((t & j2) == 0);
          v = keepMin ? (v < o ? v : o) : (v > o ? v : o);
        }
      }
      if (t < KNN) neigh[t] = (int)(v & 0x1FFFu);
      if (t == 255) neigh[32] = i;
    } else {
      // exact serial fallback on (u, j) ranks (>64 quads tied exactly at Q)
      u64 lv = ~0ull; int lm = 0;
      #pragma unroll
      for (int m = 0; m < 24; ++m) {
        u64 rk = ((u64)u[m] << 13) | (unsigned)JOF(m);
        if (rk < lv) { lv = rk; lm = m; }
      }
      for (int it2 = 0; it2 < KNN; ++it2) {
        u64 v = lv;
        for (int off2 = 32; off2 > 0; off2 >>= 1) {
          u64 o = __shfl_xor(v, off2);
          if (o < v) v = o;
        }
        if (lane == 0) redr[wv] = v;
        __syncthreads();
        v = redr[0];
        for (int w2 = 1; w2 < 4; ++w2) v = (redr[w2] < v) ? redr[w2] : v;
        if (t == 0) neigh[it2] = (int)(v & 0x1FFFu);
        if (v == lv) {
          #pragma unroll
          for (int m = 0; m < 24; ++m) if (m == lm) u[m] = 0xFFFFFFFFu;
          lv = ~0ull; lm = 0;
          #pragma unroll
          for (int m = 0; m < 24; ++m) {
            u64 rk = ((u64)u[m] << 13) | (unsigned)JOF(m);
            if (rk < lv) { lv = rk; lm = m; }
          }
        }
        __syncthreads();
      }
      if (t == 0) neigh[32] = i;
    }
    __syncthreads();

    // masked softmax over 33 entries
    if (t < 64) {
      float e = -FLT_MAX;
      if (t < 33) {
        float raw = f1[i] + f2[neigh[t]];
        e = raw > 0.f ? raw : 0.2f * raw;
      }
      float mx2 = e;
      #pragma unroll
      for (int off = 32; off > 0; off >>= 1) mx2 = fmaxf(mx2, __shfl_xor(mx2, off));
      float ex = (t < 33) ? expf(e - mx2) : 0.f;
      float sm = ex;
      #pragma unroll
      for (int off = 32; off > 0; off >>= 1) sm += __shfl_xor(sm, off);
      if (t < 33) attL[t] = ex / sm;
    }
    __syncthreads();

    {
      int g = t & 63, qd = t >> 6;
      float s = 0.f;
      for (int m = qd; m < 33; m += 4)
        s = fmaf(attL[m], Wh[(size_t)neigh[m] * G_DIM + g], s);
      hp4[qd][g] = s;
    }
    __syncthreads();
    if (t < 64) {
      float v = hp4[0][t] + hp4[1][t] + hp4[2][t] + hp4[3][t];
      hpf[t] = v > 0.f ? v : expm1f(v);
    }
    __syncthreads();
    if (t < NOUT) {
      float o = bc[t];
      for (int g = 0; g < 64; ++g) o = fmaf(hpf[g], WcL[g * NOUT + t], o);
      out[(size_t)i * NOUT + t] = o;
    }

    // rotate prefetched keys in
    if (r < ROWS - 1) {
      #pragma unroll
      for (int m = 0; m < 24; ++m) u[m] = uN[m];
    }
  }
}

extern "C" void kernel_launch(void* const* d_in, const int* in_sizes, int n_in,
                              void* d_out, int out_size, void* d_ws, size_t ws_size,
                              hipStream_t stream)
{
  const float* x  = (const float*)d_in[0];
  const float* W0 = (const float*)d_in[1];
  const float* b0 = (const float*)d_in[2];
  const float* W1 = (const float*)d_in[3];
  const float* b1 = (const float*)d_in[4];
  const float* gW = (const float*)d_in[5];
  const float* ga = (const float*)d_in[6];
  const float* cW = (const float*)d_in[7];
  const float* cb = (const float*)d_in[8];
  const float* dW = (const float*)d_in[9];
  const float* db = (const float*)d_in[10];
  float* out = (float*)d_out;

  char* base = (char*)d_ws;
  char* w = base;
  auto alloc = [&](size_t bytes) { char* p = w; w += (bytes + 255) & ~(size_t)255; return p; };
  u16 *W0p[3], *W1p[3], *gWp[3], *h1p[3], *hp[3];
  for (int p = 0; p < 3; ++p) W0p[p] = (u16*)alloc((size_t)D_IN * H1_DIM * 2);
  for (int p = 0; p < 3; ++p) W1p[p] = (u16*)alloc((size_t)H1_DIM * H2_DIM * 2);
  for (int p = 0; p < 3; ++p) gWp[p] = (u16*)alloc((size_t)H2_DIM * G_DIM * 2);
  for (int p = 0; p < 3; ++p) h1p[p] = (u16*)alloc((size_t)N_PTS * H1_DIM * 2);
  for (int p = 0; p < 3; ++p) hp[p]  = (u16*)alloc((size_t)N_PTS * H2_DIM * 2);
  float* hF  = (float*)alloc((size_t)N_PTS * H2_DIM * 4);
  float* WhF = (float*)alloc((size_t)N_PTS * G_DIM * 4);
  float* sqv = (float*)alloc(N_PTS * 4);
  float* f1v = (float*)alloc(N_PTS * 4);
  float* f2v = (float*)alloc(N_PTS * 4);
  float* Wc  = (float*)alloc(64 * NOUT * 4);
  float* bc  = (float*)alloc(64 * 4);

  char* pbase = w;
  const size_t MN1 = (size_t)N_PTS * H1_DIM;
  const size_t MN2 = (size_t)N_PTS * H2_DIM;
  const size_t MN3 = (size_t)N_PTS * G_DIM;
  float* P1 = (float*)alloc(4 * MN1 * 4);
  float* P2 = (float*)alloc(4 * MN2 * 4);
  float* P3 = (float*)alloc(4 * MN3 * 4);
  float* Sb = (float*)pbase;

  size_t used_persist = (size_t)(pbase - base);
  size_t avail = (ws_size > used_persist) ? (ws_size - used_persist) / 4 : 0;
  int rowblk = 128;
  const int rcand[] = {6144, 3072, 1536, 768, 384, 256, 128};
  for (int c : rcand) { if ((size_t)c * N_PTS <= avail) { rowblk = c; break; } }

  trans_split<<<(D_IN * H1_DIM + 255) / 256, 256, 0, stream>>>(W0, W0p[0], W0p[1], W0p[2], D_IN, H1_DIM);
  trans_split<<<(H1_DIM * H2_DIM + 255) / 256, 256, 0, stream>>>(W1, W1p[0], W1p[1], W1p[2], H1_DIM, H2_DIM);
  trans_split<<<(H2_DIM * G_DIM + 255) / 256, 256, 0, stream>>>(gW, gWp[0], gWp[1], gWp[2], H2_DIM, G_DIM);
  prep_head<<<1, 256, 0, stream>>>(cW, cb, dW, db, Wc, bc);

  mfma_gemm<64, true, true, false, false, false, false, false>
      <<<dim3(H1_DIM / 64, N_PTS / 64, 4), 256, 0, stream>>>(
      x, nullptr, nullptr, W0p[0], W0p[1], W0p[2], nullptr,
      P1, nullptr, nullptr, nullptr, D_IN, D_IN / 4, H1_DIM, MN1, 0);
  combine<4, true, true, false, true><<<(int)(MN1 / 1024), 256, 0, stream>>>(
      P1, b0, MN1, H1_DIM, nullptr, h1p[0], h1p[1], h1p[2]);

  mfma_gemm<64, false, true, false, false, false, false, false>
      <<<dim3(H2_DIM / 64, N_PTS / 64, 4), 256, 0, stream>>>(
      h1p[0], h1p[1], h1p[2], W1p[0], W1p[1], W1p[2], nullptr,
      P2, nullptr, nullptr, nullptr, H1_DIM, H1_DIM / 4, H2_DIM, MN2, 0);
  combine<4, true, true, true, true><<<(int)(MN2 / 1024), 256, 0, stream>>>(
      P2, b1, MN2, H2_DIM, hF, hp[0], hp[1], hp[2]);

  mfma_gemm<64, false, true, false, false, false, false, false>
      <<<dim3(G_DIM / 64, N_PTS / 64, 4), 256, 0, stream>>>(
      hp[0], hp[1], hp[2], gWp[0], gWp[1], gWp[2], nullptr,
      P3, nullptr, nullptr, nullptr, H2_DIM, H2_DIM / 4, G_DIM, MN3, 0);
  combine<4, false, false, true, false><<<(int)(MN3 / 1024), 256, 0, stream>>>(
      P3, nullptr, MN3, G_DIM, WhF, nullptr, nullptr, nullptr);

  row_stats<<<N_PTS / 256, 256, 0, stream>>>(hF, WhF, ga, sqv, f1v, f2v);

  // Gram panel(s) writing sortable keys directly, then fused select/att/head
  for (int b = 0; b < N_PTS / rowblk; ++b) {
    mfma_gemm<128, false, false, false, false, false, false, true>
        <<<dim3(N_PTS / 64, rowblk / 128, 1), 256, 0, stream>>>(
        hp[0] + (size_t)b * rowblk * H2_DIM, hp[1] + (size_t)b * rowblk * H2_DIM,
        hp[2] + (size_t)b * rowblk * H2_DIM, hp[0], hp[1], hp[2], sqv,
        Sb, nullptr, nullptr, nullptr, H2_DIM, H2_DIM, N_PTS, 0, b * rowblk);
    topk_att<<<rowblk / ROWS, 256, 0, stream>>>((const unsigned*)Sb, f1v, f2v, WhF, Wc, bc, out, b * rowblk);
  }
}

// Round 12
// 187.926 us; speedup vs baseline: 1.5214x; 1.5214x over previous
//
#include <hip/hip_runtime.h>
#include <float.h>

#define N_PTS 6144
#define D_IN  512
#define H1_DIM 256
#define H2_DIM 128
#define G_DIM  64
#define KNN    32
#define NOUT   22

typedef short s8v __attribute__((ext_vector_type(8)));   // 8 bf16 in 4 VGPR
typedef float f32x4 __attribute__((ext_vector_type(4)));
typedef unsigned u32x4 __attribute__((ext_vector_type(4)));
typedef unsigned short u16;
typedef unsigned long long u64;

__device__ __forceinline__ u16 f2bf(float f) {
  unsigned u = __float_as_uint(f);
  u += 0x7FFFu + ((u >> 16) & 1u);          // RNE to bf16
  return (u16)(u >> 16);
}
__device__ __forceinline__ float bf2f(u16 s) {
  return __uint_as_float(((unsigned)s) << 16);
}
__device__ __forceinline__ void split3(float v, u16& a0, u16& a1, u16& a2) {
  a0 = f2bf(v);
  float r1 = v - bf2f(a0);
  a1 = f2bf(r1);
  a2 = f2bf(r1 - bf2f(a1));
}

// ---------------------------------------------------------------------------
// MFMA GEMM, 3-way bf16 split, 6-term schedule (fp32-equivalent).
// C[M,N] = A[M,K] * B^T[N,K].  BN=64, BK=32, 4 waves (2x2), wave tile (BM/2)x32.
// WKEY: epilogue writes sortable-u32 kNN keys (sq[col] - 2*val; diag=UINT_MAX).
// ---------------------------------------------------------------------------
template<int BM, bool AF32, bool SPLITK, bool BIAS, bool RELU, bool WF32, bool WSPLIT, bool WKEY>
__global__ __launch_bounds__(256, 4) void mfma_gemm(
    const void* __restrict__ A0any, const u16* __restrict__ A1_, const u16* __restrict__ A2_,
    const u16* __restrict__ B0_, const u16* __restrict__ B1_, const u16* __restrict__ B2_,
    const float* __restrict__ bias,
    float* __restrict__ Cf, u16* __restrict__ C0, u16* __restrict__ C1, u16* __restrict__ C2,
    int Ktot, int Ks, int ldC, size_t MN, int rowoff)
{
  const int MT = BM / 32, NT = 2;
  __shared__ u16 lds[(BM + 64) * 32 * 3];
  u16* Ap[3] = { lds, lds + BM * 32, lds + 2 * BM * 32 };
  u16* Bp[3] = { lds + 3 * BM * 32, lds + 3 * BM * 32 + 2048, lds + 3 * BM * 32 + 4096 };

  const int t = threadIdx.x;
  const int lane = t & 63, wave = t >> 6;
  const int wm = wave >> 1, wn = wave & 1;
  const int m0 = blockIdx.y * BM, n0 = blockIdx.x * 64;
  const int kz = blockIdx.z * Ks;

  f32x4 acc[MT][NT] = {};

  for (int k0 = 0; k0 < Ks; k0 += 32) {
    if (k0) __syncthreads();
    const int kb = kz + k0;
    if (AF32) {
      const float* A = (const float*)A0any;
      #pragma unroll
      for (int c0 = 0; c0 < BM * 4; c0 += 256) {
        int c = c0 + t;
        int row = c >> 2, slot = c & 3;
        const float* g = A + (size_t)(m0 + row) * Ktot + kb + slot * 8;
        f32x4 fa = *(const f32x4*)g;
        f32x4 fb = *(const f32x4*)(g + 4);
        int dst = row * 32 + ((slot ^ ((row >> 1) & 3)) << 3);
        s8v v0, v1, v2;
        #pragma unroll
        for (int e = 0; e < 4; ++e) {
          u16 a0, a1, a2; split3(fa[e], a0, a1, a2);
          v0[e] = (short)a0; v1[e] = (short)a1; v2[e] = (short)a2;
        }
        #pragma unroll
        for (int e = 0; e < 4; ++e) {
          u16 a0, a1, a2; split3(fb[e], a0, a1, a2);
          v0[4 + e] = (short)a0; v1[4 + e] = (short)a1; v2[4 + e] = (short)a2;
        }
        *(s8v*)(Ap[0] + dst) = v0;
        *(s8v*)(Ap[1] + dst) = v1;
        *(s8v*)(Ap[2] + dst) = v2;
      }
    } else {
      const u16* As[3] = { (const u16*)A0any, A1_, A2_ };
      #pragma unroll
      for (int c0 = 0; c0 < BM * 4; c0 += 256) {
        int c = c0 + t;
        int row = c >> 2, slot = c & 3;
        size_t g = (size_t)(m0 + row) * Ktot + kb + slot * 8;
        int dst = row * 32 + ((slot ^ ((row >> 1) & 3)) << 3);
        #pragma unroll
        for (int p = 0; p < 3; ++p)
          *(s8v*)(Ap[p] + dst) = *(const s8v*)(As[p] + g);
      }
    }
    {
      const u16* Bs[3] = { B0_, B1_, B2_ };
      int row = t >> 2, slot = t & 3;
      size_t g = (size_t)(n0 + row) * Ktot + kb + slot * 8;
      int dst = row * 32 + ((slot ^ ((row >> 1) & 3)) << 3);
      #pragma unroll
      for (int p = 0; p < 3; ++p)
        *(s8v*)(Bp[p] + dst) = *(const s8v*)(Bs[p] + g);
    }
    __syncthreads();

    s8v af[3][MT], bf[3][NT];
    #pragma unroll
    for (int mt = 0; mt < MT; ++mt) {
      int r = wm * (BM / 2) + mt * 16 + (lane & 15);
      int off = r * 32 + (((lane >> 4) ^ ((r >> 1) & 3)) << 3);
      #pragma unroll
      for (int p = 0; p < 3; ++p) af[p][mt] = *(const s8v*)(Ap[p] + off);
    }
    #pragma unroll
    for (int nt = 0; nt < NT; ++nt) {
      int r = wn * 32 + nt * 16 + (lane & 15);
      int off = r * 32 + (((lane >> 4) ^ ((r >> 1) & 3)) << 3);
      #pragma unroll
      for (int p = 0; p < 3; ++p) bf[p][nt] = *(const s8v*)(Bp[p] + off);
    }
    #pragma unroll
    for (int mt = 0; mt < MT; ++mt)
      #pragma unroll
      for (int nt = 0; nt < NT; ++nt) {
        f32x4 a = acc[mt][nt];
        a = __builtin_amdgcn_mfma_f32_16x16x32_bf16(af[0][mt], bf[0][nt], a, 0, 0, 0);
        a = __builtin_amdgcn_mfma_f32_16x16x32_bf16(af[0][mt], bf[1][nt], a, 0, 0, 0);
        a = __builtin_amdgcn_mfma_f32_16x16x32_bf16(af[1][mt], bf[0][nt], a, 0, 0, 0);
        a = __builtin_amdgcn_mfma_f32_16x16x32_bf16(af[1][mt], bf[1][nt], a, 0, 0, 0);
        a = __builtin_amdgcn_mfma_f32_16x16x32_bf16(af[0][mt], bf[2][nt], a, 0, 0, 0);
        a = __builtin_amdgcn_mfma_f32_16x16x32_bf16(af[2][mt], bf[0][nt], a, 0, 0, 0);
        acc[mt][nt] = a;
      }
  }

  #pragma unroll
  for (int mt = 0; mt < MT; ++mt) {
    #pragma unroll
    for (int nt = 0; nt < NT; ++nt) {
      int col = n0 + wn * 32 + nt * 16 + (lane & 15);
      float bv = (BIAS && !SPLITK) ? bias[col] : 0.f;
      float sqc = WKEY ? bias[col] : 0.f;
      #pragma unroll
      for (int v = 0; v < 4; ++v) {
        int row = m0 + wm * (BM / 2) + mt * 16 + (lane >> 4) * 4 + v;
        float val = acc[mt][nt][v] + bv;
        size_t o = (size_t)row * ldC + col;
        if (SPLITK) {
          Cf[(size_t)blockIdx.z * MN + o] = val;
        } else if (WKEY) {
          float f = fmaf(-2.f, val, sqc);
          unsigned ub = __float_as_uint(f);
          unsigned uu = (ub & 0x80000000u) ? ~ub : (ub | 0x80000000u);
          if (rowoff + row == col) uu = 0xFFFFFFFFu;
          ((unsigned*)Cf)[o] = uu;
        } else {
          if (RELU) val = fmaxf(val, 0.f);
          if (WF32) Cf[o] = val;
          if (WSPLIT) {
            u16 a0, a1, a2; split3(val, a0, a1, a2);
            C0[o] = a0; C1[o] = a1; C2[o] = a2;
          }
        }
      }
    }
  }
}

template<int S, bool BIAS, bool RELU, bool WF32, bool WSPLIT>
__global__ void combine(const float* __restrict__ P, const float* __restrict__ bias,
                        size_t MN, int Ncols,
                        float* __restrict__ Cf, u16* __restrict__ C0,
                        u16* __restrict__ C1, u16* __restrict__ C2)
{
  size_t idx = ((size_t)blockIdx.x * 256 + threadIdx.x) * 4;
  if (idx >= MN) return;
  f32x4 s = *(const f32x4*)(P + idx);
  #pragma unroll
  for (int z = 1; z < S; ++z) s += *(const f32x4*)(P + (size_t)z * MN + idx);
  int n = (int)(idx % (size_t)Ncols);
  #pragma unroll
  for (int e = 0; e < 4; ++e) {
    float v = s[e] + (BIAS ? bias[n + e] : 0.f);
    if (RELU) v = fmaxf(v, 0.f);
    if (WF32) Cf[idx + e] = v;
    if (WSPLIT) {
      u16 a0, a1, a2; split3(v, a0, a1, a2);
      C0[idx + e] = a0; C1[idx + e] = a1; C2[idx + e] = a2;
    }
  }
}

__global__ void trans_split(const float* __restrict__ W, u16* __restrict__ p0,
                            u16* __restrict__ p1, u16* __restrict__ p2, int K, int N)
{
  int id = blockIdx.x * 256 + threadIdx.x;
  if (id >= K * N) return;
  int k = id / N, n = id % N;
  u16 a0, a1, a2;
  split3(W[id], a0, a1, a2);
  size_t o = (size_t)n * K + k;
  p0[o] = a0; p1[o] = a1; p2[o] = a2;
}

__global__ void prep_head(const float* __restrict__ cW, const float* __restrict__ cb,
                          const float* __restrict__ dW, const float* __restrict__ db,
                          float* __restrict__ Wc, float* __restrict__ bc)
{
  int t = threadIdx.x;
  for (int idx = t; idx < 64 * NOUT; idx += 256) {
    int g = idx / NOUT, c = idx % NOUT;
    float s = 0.f;
    if (c < 16) {
      for (int r = 0; r < 8; ++r) s += cW[(r * 64 + g) * 16 + c];
    } else {
      int k = (c - 16) >> 1, o = (c - 16) & 1;
      for (int r = 0; r < 8; ++r) s += dW[k * 1024 + (r * 64 + g) * 2 + o];
    }
    Wc[idx] = s;
  }
  if (t < NOUT) bc[t] = (t < 16) ? cb[t] : db[t - 16];
}

__global__ void row_stats(const float* __restrict__ h, const float* __restrict__ Wh,
                          const float* __restrict__ ga, float* __restrict__ sq,
                          float* __restrict__ f1, float* __restrict__ f2)
{
  int i = blockIdx.x * 256 + threadIdx.x;
  const float* hr = h + (size_t)i * H2_DIM;
  float s = 0.f;
  for (int k = 0; k < H2_DIM; ++k) { float v = hr[k]; s = fmaf(v, v, s); }
  sq[i] = s;
  const float* wr = Wh + (size_t)i * G_DIM;
  float a = 0.f, b = 0.f;
  for (int g = 0; g < G_DIM; ++g) {
    float w = wr[g];
    a = fmaf(w, ga[g], a);
    b = fmaf(w, ga[G_DIM + g], b);
  }
  f1[i] = a; f2[i] = b;
}

// ---------------------------------------------------------------------------
// ONE WAVE PER ROW (4 rows/block, no block barriers after WcL load).
// Per wave: 24 quads/lane quad-min tournament -> wave-local quaternary
// bisection (shfl only) for Q = exact 32nd-smallest quad-min -> ballot-prefix
// collection (quad reload from L2) -> register 128-elem bitonic (2/lane) on
// (key<<13|j) -> exact top-32 with np tie-break. Rare >32-quad tie case:
// in-LDS 256-elem sort (up to 64 quads). Then wave-local softmax + PV + head.
// ---------------------------------------------------------------------------
__global__ __launch_bounds__(256) void topk_att(const unsigned* __restrict__ Sb,
    const float* __restrict__ f1, const float* __restrict__ f2,
    const float* __restrict__ Wh, const float* __restrict__ Wc, const float* __restrict__ bc,
    float* __restrict__ out, int m0)
{
  const int t = threadIdx.x;
  const int lane = t & 63, wv = t >> 6;
  const int row4 = blockIdx.x * 4 + wv;
  const int i = m0 + row4;
  const unsigned* Srow = Sb + (size_t)row4 * N_PTS;

  __shared__ float WcL[64 * NOUT];
  __shared__ u64 candS[4][256];
  __shared__ int neighS[4][33];
  __shared__ float attS[4][33];
  __shared__ float hpfS[4][64];

  for (int idx = t; idx < 64 * NOUT; idx += 256) WcL[idx] = Wc[idx];
  __syncthreads();                       // only block barrier

  // ---- stream row, keep quad-mins: j = (c<<8) + (lane<<2) + e ----
  unsigned q[24];
  #pragma unroll
  for (int c = 0; c < 24; ++c) {
    u32x4 v = *(const u32x4*)(Srow + (c << 8) + (lane << 2));
    unsigned a = v[0] < v[1] ? v[0] : v[1];
    unsigned b = v[2] < v[3] ? v[2] : v[3];
    q[c] = a < b ? a : b;
  }

  // interval: lo = wavemin-1; hi = max of per-lane mins (count >= 64 >= 32)
  unsigned mnl = q[0];
  #pragma unroll
  for (int c = 1; c < 24; ++c) mnl = q[c] < mnl ? q[c] : mnl;
  unsigned mxl = mnl;
  #pragma unroll
  for (int off = 32; off > 0; off >>= 1) {
    unsigned o1 = __shfl_xor(mnl, off); mnl = o1 < mnl ? o1 : mnl;
    unsigned o2 = __shfl_xor(mxl, off); mxl = o2 > mxl ? o2 : mxl;
  }

  // quaternary bisection on the wave's 1536 quad-mins (wave-local)
  long long lo = (long long)mnl - 1, hi = (long long)mxl;
  while (hi - lo > 1) {
    long long span = hi - lo;
    unsigned m1 = (unsigned)(lo + (span >> 2));
    unsigned m2 = (unsigned)(lo + (span >> 1));
    unsigned m3 = (unsigned)(hi - (span >> 2));
    int c1 = 0, c2 = 0, c3 = 0;
    #pragma unroll
    for (int c = 0; c < 24; ++c) {
      c1 += (q[c] <= m1);
      c2 += (q[c] <= m2);
      c3 += (q[c] <= m3);
    }
    #pragma unroll
    for (int off = 32; off > 0; off >>= 1) {
      c1 += __shfl_xor(c1, off);
      c2 += __shfl_xor(c2, off);
      c3 += __shfl_xor(c3, off);
    }
    if (c1 >= KNN)       { hi = m1; }
    else if (c2 >= KNN)  { lo = m1; hi = m2; }
    else if (c3 >= KNN)  { lo = m2; hi = m3; }
    else                 { lo = m3; }
  }
  const unsigned Q = (unsigned)hi;

  // ---- ballot-prefix collection of qualifying quads (reload from L2) ----
  candS[wv][lane] = ~0ull;
  candS[wv][64 + lane] = ~0ull;
  const u64 below = (lane == 0) ? 0ull : (~0ull >> (64 - lane));
  int cnt = 0;
  #pragma unroll
  for (int c = 0; c < 24; ++c) {
    bool act = (q[c] <= Q);
    u64 mask = __ballot(act);
    if (act) {
      int pos = cnt + (int)__popcll(mask & below);
      if (pos < 32) {
        u32x4 v = *(const u32x4*)(Srow + (c << 8) + (lane << 2));
        #pragma unroll
        for (int e = 0; e < 4; ++e) {
          int j = (c << 8) + (lane << 2) + e;
          candS[wv][pos * 4 + e] = ((u64)v[e] << 13) | (unsigned)j;
        }
      }
    }
    cnt += (int)__popcll(mask);
  }

  if (cnt <= 32) {
    // ---- register bitonic sort of 128 candidates, 2 elems/lane ----
    u64 v0 = candS[wv][2 * lane], v1 = candS[wv][2 * lane + 1];
    const int e0 = 2 * lane, e1 = e0 + 1;
    for (int k = 2; k <= 128; k <<= 1) {
      for (int j = k >> 1; j >= 2; j >>= 1) {
        int half = j >> 1;
        u64 o0 = __shfl_xor(v0, half);
        u64 o1 = __shfl_xor(v1, half);
        bool up0 = ((e0 & k) == 0) == ((e0 & j) == 0);
        bool up1 = ((e1 & k) == 0) == ((e1 & j) == 0);
        v0 = up0 ? (v0 < o0 ? v0 : o0) : (v0 > o0 ? v0 : o0);
        v1 = up1 ? (v1 < o1 ? v1 : o1) : (v1 > o1 ? v1 : o1);
      }
      bool asc = ((e0 & k) == 0);
      u64 a = v0 < v1 ? v0 : v1, b = v0 < v1 ? v1 : v0;
      v0 = asc ? a : b;
      v1 = asc ? b : a;
    }
    if (lane < 16) {
      neighS[wv][2 * lane]     = (int)(v0 & 0x1FFFu);
      neighS[wv][2 * lane + 1] = (int)(v1 & 0x1FFFu);
    }
    if (lane == 0) neighS[wv][32] = i;
  } else {
    // rare: up to 64 quads (ties at Q). Collect pos<64, in-LDS 256 sort.
    candS[wv][128 + lane] = ~0ull;
    candS[wv][192 + lane] = ~0ull;
    int cnt2 = 0;
    #pragma unroll
    for (int c = 0; c < 24; ++c) {
      bool act = (q[c] <= Q);
      u64 mask = __ballot(act);
      if (act) {
        int pos = cnt2 + (int)__popcll(mask & below);
        if (pos < 64) {
          u32x4 v = *(const u32x4*)(Srow + (c << 8) + (lane << 2));
          #pragma unroll
          for (int e = 0; e < 4; ++e) {
            int j = (c << 8) + (lane << 2) + e;
            candS[wv][pos * 4 + e] = ((u64)v[e] << 13) | (unsigned)j;
          }
        }
      }
      cnt2 += (int)__popcll(mask);
    }
    for (int k = 2; k <= 256; k <<= 1) {
      for (int j = k >> 1; j >= 1; j >>= 1) {
        #pragma unroll
        for (int s = 0; s < 4; ++s) {
          int e = lane + s * 64;
          int p = e ^ j;
          if (p > e) {
            u64 a = candS[wv][e], b = candS[wv][p];
            bool asc = ((e & k) == 0);
            if ((a > b) == asc) { candS[wv][e] = b; candS[wv][p] = a; }
          }
        }
      }
    }
    if (lane < KNN) neighS[wv][lane] = (int)(candS[wv][lane] & 0x1FFFu);
    if (lane == 0) neighS[wv][32] = i;
  }

  // ---- wave-local masked softmax over 33 entries ----
  {
    float e = -FLT_MAX;
    if (lane < 33) {
      float raw = f1[i] + f2[neighS[wv][lane]];
      e = raw > 0.f ? raw : 0.2f * raw;
    }
    float mx = e;
    #pragma unroll
    for (int off = 32; off > 0; off >>= 1) mx = fmaxf(mx, __shfl_xor(mx, off));
    float ex = (lane < 33) ? expf(e - mx) : 0.f;
    float sm = ex;
    #pragma unroll
    for (int off = 32; off > 0; off >>= 1) sm += __shfl_xor(sm, off);
    if (lane < 33) attS[wv][lane] = ex / sm;
  }

  // ---- PV: lane = g; hp[g] = sum_m att[m] * Wh[neigh[m]][g]; elu ----
  {
    float s = 0.f;
    for (int m = 0; m < 33; ++m)
      s = fmaf(attS[wv][m], Wh[(size_t)neighS[wv][m] * G_DIM + lane], s);
    hpfS[wv][lane] = s > 0.f ? s : expm1f(s);
  }

  // ---- head: 64 -> 22 ----
  if (lane < NOUT) {
    float o = bc[lane];
    for (int g = 0; g < 64; ++g) o = fmaf(hpfS[wv][g], WcL[g * NOUT + lane], o);
    out[(size_t)i * NOUT + lane] = o;
  }
}

extern "C" void kernel_launch(void* const* d_in, const int* in_sizes, int n_in,
                              void* d_out, int out_size, void* d_ws, size_t ws_size,
                              hipStream_t stream)
{
  const float* x  = (const float*)d_in[0];
  const float* W0 = (const float*)d_in[1];
  const float* b0 = (const float*)d_in[2];
  const float* W1 = (const float*)d_in[3];
  const float* b1 = (const float*)d_in[4];
  const float* gW = (const float*)d_in[5];
  const float* ga = (const float*)d_in[6];
  const float* cW = (const float*)d_in[7];
  const float* cb = (const float*)d_in[8];
  const float* dW = (const float*)d_in[9];
  const float* db = (const float*)d_in[10];
  float* out = (float*)d_out;

  char* base = (char*)d_ws;
  char* w = base;
  auto alloc = [&](size_t bytes) { char* p = w; w += (bytes + 255) & ~(size_t)255; return p; };
  u16 *W0p[3], *W1p[3], *gWp[3], *h1p[3], *hp[3];
  for (int p = 0; p < 3; ++p) W0p[p] = (u16*)alloc((size_t)D_IN * H1_DIM * 2);
  for (int p = 0; p < 3; ++p) W1p[p] = (u16*)alloc((size_t)H1_DIM * H2_DIM * 2);
  for (int p = 0; p < 3; ++p) gWp[p] = (u16*)alloc((size_t)H2_DIM * G_DIM * 2);
  for (int p = 0; p < 3; ++p) h1p[p] = (u16*)alloc((size_t)N_PTS * H1_DIM * 2);
  for (int p = 0; p < 3; ++p) hp[p]  = (u16*)alloc((size_t)N_PTS * H2_DIM * 2);
  float* hF  = (float*)alloc((size_t)N_PTS * H2_DIM * 4);
  float* WhF = (float*)alloc((size_t)N_PTS * G_DIM * 4);
  float* sqv = (float*)alloc(N_PTS * 4);
  float* f1v = (float*)alloc(N_PTS * 4);
  float* f2v = (float*)alloc(N_PTS * 4);
  float* Wc  = (float*)alloc(64 * NOUT * 4);
  float* bc  = (float*)alloc(64 * 4);

  char* pbase = w;
  const size_t MN1 = (size_t)N_PTS * H1_DIM;
  const size_t MN2 = (size_t)N_PTS * H2_DIM;
  const size_t MN3 = (size_t)N_PTS * G_DIM;
  float* P1 = (float*)alloc(4 * MN1 * 4);
  float* P2 = (float*)alloc(4 * MN2 * 4);
  float* P3 = (float*)alloc(4 * MN3 * 4);
  float* Sb = (float*)pbase;

  size_t used_persist = (size_t)(pbase - base);
  size_t avail = (ws_size > used_persist) ? (ws_size - used_persist) / 4 : 0;
  int rowblk = 128;
  const int rcand[] = {6144, 3072, 1536, 768, 384, 256, 128};
  for (int c : rcand) { if ((size_t)c * N_PTS <= avail) { rowblk = c; break; } }

  trans_split<<<(D_IN * H1_DIM + 255) / 256, 256, 0, stream>>>(W0, W0p[0], W0p[1], W0p[2], D_IN, H1_DIM);
  trans_split<<<(H1_DIM * H2_DIM + 255) / 256, 256, 0, stream>>>(W1, W1p[0], W1p[1], W1p[2], H1_DIM, H2_DIM);
  trans_split<<<(H2_DIM * G_DIM + 255) / 256, 256, 0, stream>>>(gW, gWp[0], gWp[1], gWp[2], H2_DIM, G_DIM);
  prep_head<<<1, 256, 0, stream>>>(cW, cb, dW, db, Wc, bc);

  mfma_gemm<64, true, true, false, false, false, false, false>
      <<<dim3(H1_DIM / 64, N_PTS / 64, 4), 256, 0, stream>>>(
      x, nullptr, nullptr, W0p[0], W0p[1], W0p[2], nullptr,
      P1, nullptr, nullptr, nullptr, D_IN, D_IN / 4, H1_DIM, MN1, 0);
  combine<4, true, true, false, true><<<(int)(MN1 / 1024), 256, 0, stream>>>(
      P1, b0, MN1, H1_DIM, nullptr, h1p[0], h1p[1], h1p[2]);

  mfma_gemm<64, false, true, false, false, false, false, false>
      <<<dim3(H2_DIM / 64, N_PTS / 64, 4), 256, 0, stream>>>(
      h1p[0], h1p[1], h1p[2], W1p[0], W1p[1], W1p[2], nullptr,
      P2, nullptr, nullptr, nullptr, H1_DIM, H1_DIM / 4, H2_DIM, MN2, 0);
  combine<4, true, true, true, true><<<(int)(MN2 / 1024), 256, 0, stream>>>(
      P2, b1, MN2, H2_DIM, hF, hp[0], hp[1], hp[2]);

  mfma_gemm<64, false, true, false, false, false, false, false>
      <<<dim3(G_DIM / 64, N_PTS / 64, 4), 256, 0, stream>>>(
      hp[0], hp[1], hp[2], gWp[0], gWp[1], gWp[2], nullptr,
      P3, nullptr, nullptr, nullptr, H2_DIM, H2_DIM / 4, G_DIM, MN3, 0);
  combine<4, false, false, true, false><<<(int)(MN3 / 1024), 256, 0, stream>>>(
      P3, nullptr, MN3, G_DIM, WhF, nullptr, nullptr, nullptr);

  row_stats<<<N_PTS / 256, 256, 0, stream>>>(hF, WhF, ga, sqv, f1v, f2v);

  // Gram panel(s) writing sortable keys directly, then fused select/att/head
  for (int b = 0; b < N_PTS / rowblk; ++b) {
    mfma_gemm<128, false, false, false, false, false, false, true>
        <<<dim3(N_PTS / 64, rowblk / 128, 1), 256, 0, stream>>>(
        hp[0] + (size_t)b * rowblk * H2_DIM, hp[1] + (size_t)b * rowblk * H2_DIM,
        hp[2] + (size_t)b * rowblk * H2_DIM, hp[0], hp[1], hp[2], sqv,
        Sb, nullptr, nullptr, nullptr, H2_DIM, H2_DIM, N_PTS, 0, b * rowblk);
    topk_att<<<rowblk / 4, 256, 0, stream>>>((const unsigned*)Sb, f1v, f2v, WhF, Wc, bc, out, b * rowblk);
  }
}